// Round 6
// baseline (495.452 us; speedup 1.0000x reference)
//
#include <hip/hip_runtime.h>
#include <stddef.h>

#define NN 512
#define CC 128
#define NPOS (NN*NN)
#define CPITCH (NPOS + 512)

typedef unsigned short u16;
typedef unsigned int   u32;
typedef u16  u16x4  __attribute__((ext_vector_type(4)));
typedef u16  u16x8  __attribute__((ext_vector_type(8)));
typedef __bf16 bf16x8 __attribute__((ext_vector_type(8)));
typedef float f32x4  __attribute__((ext_vector_type(4)));

__device__ __forceinline__ float b2f(u16 u) {
    union { u32 i; float f; } w; w.i = ((u32)u) << 16; return w.f;
}
__device__ __forceinline__ u16 f2b(float f) {
    return __builtin_bit_cast(u16, (__bf16)f);
}
__device__ __forceinline__ float sigm(float x) { return 1.0f / (1.0f + __expf(-x)); }

__device__ __forceinline__ void gld16(const u16* g, u16* l) {
    __builtin_amdgcn_global_load_lds(
        (const __attribute__((address_space(1))) u32*)g,
        (__attribute__((address_space(3))) u32*)l, 16, 0, 0);
}

struct W6 { const float* p[6]; };   // 0:agw 1:apw 2:bgw 3:bpw 4:gw 5:zw

// ---------------------------------------------------------------------------
// K0: pack 6 [128x128] f32 weight matrices into bf16 MFMA-fragment order.
// When wo != nullptr, slot 5 (zw) is pre-folded: W'[o][c] = wo[c]*zw[o][c]
// (LayerNorm-fold for k3_out_fold).
// ---------------------------------------------------------------------------
__global__ __launch_bounds__(256) void k0_pack(W6 w, const float* __restrict__ wo,
                                               u16* __restrict__ dst)
{
    const int i = blockIdx.x * 256 + threadIdx.x;     // 6*16384 total
    const int mt = i >> 14, r = i & 16383;
    const int cb = r >> 11, ks = (r >> 9) & 3, lane = (r >> 3) & 63, j = r & 7;
    const int row = cb * 16 + (lane & 15);
    const int col = ks * 32 + (lane >> 4) * 8 + j;
    float v = w.p[mt][row * 128 + col];
    if (wo && mt == 5) v *= wo[col];
    dst[i] = f2b(v);
}

// ---------------------------------------------------------------------------
// K0b: fold constants for k3: s12[o] = S1[o] = sum_c bo[c]*zw[o][c],
//                             s12[128+o] = S2[o] = sum_c wo[c]*zw[o][c].
// ---------------------------------------------------------------------------
__global__ __launch_bounds__(128) void k0_s12(
    const float* __restrict__ zw, const float* __restrict__ wo,
    const float* __restrict__ bo, float* __restrict__ s12)
{
    const int o = threadIdx.x;
    float s1 = 0.f, s2 = 0.f;
    #pragma unroll 4
    for (int c = 0; c < 128; ++c) {
        const float zv = zw[o * 128 + c];
        s1 += bo[c] * zv;
        s2 += wo[c] * zv;
    }
    s12[o] = s1; s12[128 + o] = s2;
}

// ---------------------------------------------------------------------------
// K1: LayerNorm(z) + 4 gated projections, MFMA. r4 structure (best measured):
// 64 positions/block, 128 threads; writes zn (bf16 position-major) for k3.
// ---------------------------------------------------------------------------
__global__ __launch_bounds__(128) void k1_ln_proj(
    const float* __restrict__ z,  const float* __restrict__ mask,
    const float* __restrict__ wi, const float* __restrict__ bi,
    const u16* __restrict__ wpk,
    const float* __restrict__ agb, const float* __restrict__ apb,
    const float* __restrict__ bgb, const float* __restrict__ bpb,
    u16* __restrict__ a_cm, u16* __restrict__ b_cm,
    u16* __restrict__ zn_pm)
{
    __shared__ u16 zn[64][136];   // bf16 normalized z, pitch 136
    const int tid = threadIdx.x;
    const size_t p0 = (size_t)blockIdx.x * 64;

    {   // ---- LayerNorm, coalesced: 32-lane group co-owns one row ----
        const float* zt = z + p0 * CC;
        const int g  = tid >> 5;            // row-group
        const int c4 = (tid & 31) * 4;      // channel base
        const f32x4 wi4 = *(const f32x4*)(wi + c4);
        const f32x4 bi4 = *(const f32x4*)(bi + c4);
        f32x4 v[16];
        #pragma unroll
        for (int h = 0; h < 16; ++h)
            v[h] = *(const f32x4*)(zt + h * 512 + tid * 4);
        #pragma unroll
        for (int h = 0; h < 16; ++h) {
            float s  = (v[h][0] + v[h][1]) + (v[h][2] + v[h][3]);
            float s2 = (v[h][0]*v[h][0] + v[h][1]*v[h][1])
                     + (v[h][2]*v[h][2] + v[h][3]*v[h][3]);
            #pragma unroll
            for (int ms = 1; ms <= 16; ms <<= 1) {
                s  += __shfl_xor(s,  ms);
                s2 += __shfl_xor(s2, ms);
            }
            const float mu   = s * (1.0f / CC);
            const float rstd = rsqrtf(s2 * (1.0f / CC) - mu * mu + 1e-5f);
            u16x4 o4;
            #pragma unroll
            for (int e = 0; e < 4; ++e) {
                const float nw = rstd * wi4[e];
                o4[e] = f2b(v[h][e] * nw + __builtin_fmaf(-mu, nw, bi4[e]));
            }
            *(u16x4*)&zn[h * 4 + g][c4] = o4;
            if (zn_pm)
                *(u16x4*)(zn_pm + (p0 + h * 4 + g) * CC + c4) = o4;
        }
    }
    __syncthreads();

    const int wave = tid >> 6, lane = tid & 63;
    const int m = lane & 15, q = lane >> 4;

    bf16x8 af[2][4];
    #pragma unroll
    for (int t = 0; t < 2; ++t)
        #pragma unroll
        for (int ks = 0; ks < 4; ++ks)
            af[t][ks] = *(const bf16x8*)&zn[wave * 32 + t * 16 + m][ks * 32 + q * 8];

    f32x4 mkv[2];
    #pragma unroll
    for (int t = 0; t < 2; ++t)
        mkv[t] = *(const f32x4*)(mask + p0 + wave * 32 + t * 16 + q * 4);

    const float* Bv[4] = { agb, apb, bgb, bpb };

    for (int cb = 0; cb < 8; ++cb) {
        const int o = cb * 16 + m;
        f32x4 res[4][2];
        #pragma unroll
        for (int mt = 0; mt < 4; ++mt) {
            const float bvv = Bv[mt][o];
            #pragma unroll
            for (int t = 0; t < 2; ++t) res[mt][t] = f32x4{ bvv, bvv, bvv, bvv };
            const u16* wp = wpk + ((size_t)((mt * 8 + cb) * 4)) * 512 + (size_t)lane * 8;
            bf16x8 wf[4];
            #pragma unroll
            for (int ks = 0; ks < 4; ++ks) wf[ks] = *(const bf16x8*)(wp + ks * 512);
            #pragma unroll
            for (int ks = 0; ks < 4; ++ks)
                #pragma unroll
                for (int t = 0; t < 2; ++t)
                    res[mt][t] = __builtin_amdgcn_mfma_f32_16x16x32_bf16(
                                   af[t][ks], wf[ks], res[mt][t], 0, 0, 0);
        }
        #pragma unroll
        for (int t = 0; t < 2; ++t) {
            u16x4 av, bv;
            #pragma unroll
            for (int r = 0; r < 4; ++r) {
                const float mk = mkv[t][r];
                av[r] = f2b(mk * sigm(res[0][t][r]) * res[1][t][r]);
                bv[r] = f2b(mk * sigm(res[2][t][r]) * res[3][t][r]);
            }
            const size_t off = (size_t)o * CPITCH + p0 + wave * 32 + t * 16 + q * 4;
            *(u16x4*)(a_cm + off) = av;
            *(u16x4*)(b_cm + off) = bv;
        }
    }
}

// ---------------------------------------------------------------------------
// K2: per-channel 512x512x512 NT GEMM, MFMA (m97 structure), XCD-affine.
// ---------------------------------------------------------------------------
__global__ __launch_bounds__(256) void k2_gemm(
    const u16* __restrict__ A, const u16* __restrict__ B, u16* __restrict__ X)
{
    __shared__ u16 As[2][128][32];
    __shared__ u16 Bs[2][128][32];
    const int tid = threadIdx.x;
    const int bx  = blockIdx.x;
    const int xcd  = bx & 7;
    const int slot = bx >> 3;              // 0..255 per XCD
    const int c    = (slot >> 4) * 8 + xcd;
    const int tile = slot & 15;
    const int i0   = (tile >> 2) * 128;
    const int j0   = (tile & 3) * 128;
    const size_t cbase = (size_t)c * CPITCH;
    const u16* Ac = A + cbase;
    const u16* Bc = B + cbase;

    const int wave = tid >> 6, lane = tid & 63;
    const int wm = wave >> 1, wn = wave & 1;
    const int m = lane & 15, q = lane >> 4;

    f32x4 acc[4][4];
    const f32x4 zero = { 0.f, 0.f, 0.f, 0.f };
    #pragma unroll
    for (int mt = 0; mt < 4; ++mt)
        #pragma unroll
        for (int nt = 0; nt < 4; ++nt) acc[mt][nt] = zero;

    for (int kt = 0; kt < 8; ++kt) {
        __syncthreads();
        #pragma unroll
        for (int ps = 0; ps < 4; ++ps) {
            const int id   = ps * 256 + tid;
            const int half = id >> 9;
            const int rw   = (id >> 2) & 127;
            const int g    = (id & 3) ^ ((rw >> 1) & 3);
            const size_t goff = (size_t)(kt * 64 + half * 32 + g * 8);
            gld16(Ac + (size_t)(i0 + rw) * NN + goff, &As[0][0][0] + id * 8);
            gld16(Bc + (size_t)(j0 + rw) * NN + goff, &Bs[0][0][0] + id * 8);
        }
        __syncthreads();
        #pragma unroll
        for (int ks = 0; ks < 2; ++ks) {
            bf16x8 af[4], bf[4];
            #pragma unroll
            for (int mt = 0; mt < 4; ++mt) {
                const int row = wm * 64 + mt * 16 + m;
                const int slt = q ^ ((row >> 1) & 3);
                af[mt] = *(const bf16x8*)&As[ks][row][slt * 8];
            }
            #pragma unroll
            for (int nt = 0; nt < 4; ++nt) {
                const int row = wn * 64 + nt * 16 + m;
                const int slt = q ^ ((row >> 1) & 3);
                bf[nt] = *(const bf16x8*)&Bs[ks][row][slt * 8];
            }
            #pragma unroll
            for (int mt = 0; mt < 4; ++mt)
                #pragma unroll
                for (int nt = 0; nt < 4; ++nt)
                    acc[mt][nt] = __builtin_amdgcn_mfma_f32_16x16x32_bf16(
                                    af[mt], bf[nt], acc[mt][nt], 0, 0, 0);
        }
    }

    #pragma unroll
    for (int mt = 0; mt < 4; ++mt) {
        #pragma unroll
        for (int r = 0; r < 4; ++r) {
            const int i = i0 + wm * 64 + mt * 16 + q * 4 + r;
            #pragma unroll
            for (int nt = 0; nt < 4; ++nt) {
                const int j = j0 + wn * 64 + nt * 16 + m;
                X[cbase + (size_t)i * NN + j] = f2b(acc[mt][nt][r]);
            }
        }
    }
}

// ---------------------------------------------------------------------------
// K3 (folded): out = (rstd*(x@W'^T - mu*S2) + S1 + zb) * sigmoid(zn@gw^T+gb)
// LN(x) commuted past the matmul: MFMA runs on RAW x; LN applied as a
// 2-FMA per-element epilogue correction. No xn pass, no column-read
// transpose, one barrier fewer, LDS 36 KB (was 68).
// ---------------------------------------------------------------------------
__global__ __launch_bounds__(256) void k3_out_fold(
    float* __restrict__ out, const u16* __restrict__ x_cm,
    const u16* __restrict__ zn_pm,
    const u16* __restrict__ wpk, const float* __restrict__ s12,
    const float* __restrict__ gbv, const float* __restrict__ zbv)
{
    __shared__ u16   XT[128][136];        // x tile, position-major
    __shared__ float mu_l[128], rs_l[128];
    const int tid = threadIdx.x;
    const size_t p0 = (size_t)blockIdx.x * 128;
    const int wave = tid >> 6, lane = tid & 63;
    const int m = lane & 15, q = lane >> 4;

    // ---- stage x tile: read channel-major (coalesced), scatter-write
    //      transposed into XT[pos][c] (64 ds_write_b16/thread) ----
    {
        const int c = tid >> 1, seg = tid & 1;
        #pragma unroll
        for (int e = 0; e < 8; ++e) {
            u16x8 vv = *(const u16x8*)(x_cm + (size_t)c * CPITCH + p0 + seg * 64 + e * 8);
            #pragma unroll
            for (int j = 0; j < 8; ++j)
                XT[seg * 64 + e * 8 + j][c] = vv[j];
        }
    }
    // ---- gate A-fragments direct from zn_pm (global) ----
    bf16x8 afz[2][4];
    #pragma unroll
    for (int t = 0; t < 2; ++t)
        #pragma unroll
        for (int ks = 0; ks < 4; ++ks)
            afz[t][ks] = *(const bf16x8*)(zn_pm
                           + (p0 + wave * 32 + t * 16 + m) * CC + ks * 32 + q * 8);
    // ---- per-lane fold constants (o = cb*16+m) ----
    float s1z[8], s2r[8], gb8[8];
    #pragma unroll
    for (int cb = 0; cb < 8; ++cb) {
        const int o = cb * 16 + m;
        s1z[cb] = s12[o] + zbv[o];
        s2r[cb] = s12[128 + o];
        gb8[cb] = gbv[o];
    }
    __syncthreads();

    // ---- LN stats: 32-lane group owns rows it*8+g; shfl row-reduce ----
    {
        const int g = tid >> 5, l32 = tid & 31;
        #pragma unroll 4
        for (int it = 0; it < 16; ++it) {
            const int row = it * 8 + g;
            const u16x4 xv = *(const u16x4*)&XT[row][l32 * 4];
            const float x0 = b2f(xv[0]), x1 = b2f(xv[1]),
                        x2 = b2f(xv[2]), x3 = b2f(xv[3]);
            float s  = (x0 + x1) + (x2 + x3);
            float s2 = (x0*x0 + x1*x1) + (x2*x2 + x3*x3);
            #pragma unroll
            for (int ms = 1; ms <= 16; ms <<= 1) {
                s  += __shfl_xor(s,  ms);
                s2 += __shfl_xor(s2, ms);
            }
            const float mu   = s * (1.0f / CC);
            const float rstd = rsqrtf(s2 * (1.0f / CC) - mu * mu + 1e-5f);
            if (l32 == 0) { mu_l[row] = mu; rs_l[row] = rstd; }
        }
    }
    __syncthreads();

    // ---- raw-x A-fragments from XT ----
    bf16x8 afx[2][4];
    #pragma unroll
    for (int t = 0; t < 2; ++t)
        #pragma unroll
        for (int ks = 0; ks < 4; ++ks)
            afx[t][ks] = *(const bf16x8*)&XT[wave * 32 + t * 16 + m][ks * 32 + q * 8];

    f32x4 mu4[2], rs4[2];
    #pragma unroll
    for (int t = 0; t < 2; ++t) {
        mu4[t] = *(const f32x4*)&mu_l[wave * 32 + t * 16 + q * 4];
        rs4[t] = *(const f32x4*)&rs_l[wave * 32 + t * 16 + q * 4];
    }

    for (int cb = 0; cb < 8; ++cb) {
        const int o = cb * 16 + m;
        f32x4 accg[2], accx[2];
        const f32x4 zero = { 0.f, 0.f, 0.f, 0.f };
        #pragma unroll
        for (int t = 0; t < 2; ++t) {
            const float g0 = gb8[cb];
            accg[t] = f32x4{ g0, g0, g0, g0 };
            accx[t] = zero;
        }
        const u16* wpg = wpk + ((size_t)((4 * 8 + cb) * 4)) * 512 + (size_t)lane * 8;
        const u16* wpz = wpk + ((size_t)((5 * 8 + cb) * 4)) * 512 + (size_t)lane * 8;
        bf16x8 wg[4], wz[4];
        #pragma unroll
        for (int ks = 0; ks < 4; ++ks) {
            wg[ks] = *(const bf16x8*)(wpg + ks * 512);
            wz[ks] = *(const bf16x8*)(wpz + ks * 512);
        }
        #pragma unroll
        for (int ks = 0; ks < 4; ++ks)
            #pragma unroll
            for (int t = 0; t < 2; ++t) {
                accg[t] = __builtin_amdgcn_mfma_f32_16x16x32_bf16(
                            afz[t][ks], wg[ks], accg[t], 0, 0, 0);
                accx[t] = __builtin_amdgcn_mfma_f32_16x16x32_bf16(
                            afx[t][ks], wz[ks], accx[t], 0, 0, 0);
            }
        #pragma unroll
        for (int t = 0; t < 2; ++t)
            #pragma unroll
            for (int r = 0; r < 4; ++r) {
                const size_t p = p0 + wave * 32 + t * 16 + q * 4 + r;
                const float y = rs4[t][r] * (accx[t][r] - mu4[t][r] * s2r[cb])
                              + s1z[cb];
                out[p * CC + o] = y * sigm(accg[t][r]);
            }
    }
}

// ---------------------------------------------------------------------------
// K3 (legacy fallback, used only if workspace too small for zn handoff;
// k0 then packs raw zw so this path stays correct).
// ---------------------------------------------------------------------------
__global__ __launch_bounds__(256) void k3_out(
    float* __restrict__ out, const u16* __restrict__ x_cm,
    const float* __restrict__ z,
    const float* __restrict__ wi, const float* __restrict__ bi,
    const float* __restrict__ wo, const float* __restrict__ bo,
    const u16* __restrict__ wpk,
    const float* __restrict__ gbv, const float* __restrict__ zbv)
{
    __shared__ u16 A[128][136];
    __shared__ u16 Bt[128][136];
    const int tid = threadIdx.x;
    const size_t p0 = (size_t)blockIdx.x * 128;
    const int wave = tid >> 6, lane = tid & 63;
    const int m = lane & 15, q = lane >> 4;
    const int pl = tid >> 1, ht = tid & 1;

    {
        const float* zr = z + (p0 + pl) * CC + ht * 64;
        float v[64];
        #pragma unroll
        for (int h = 0; h < 16; ++h) {
            f32x4 t = *(const f32x4*)(zr + h * 4);
            #pragma unroll
            for (int e = 0; e < 4; ++e) v[h * 4 + e] = t[e];
        }
        float s = 0.f, s2 = 0.f;
        #pragma unroll
        for (int e = 0; e < 64; ++e) { s += v[e]; s2 += v[e] * v[e]; }
        s  += __shfl_xor(s, 1);
        s2 += __shfl_xor(s2, 1);
        const float mu   = s * (1.0f / CC);
        const float rstd = rsqrtf(s2 * (1.0f / CC) - mu * mu + 1e-5f);
        #pragma unroll
        for (int h = 0; h < 8; ++h) {
            u16x8 o8;
            #pragma unroll
            for (int e = 0; e < 8; ++e) {
                const int c = ht * 64 + h * 8 + e;
                o8[e] = f2b((v[h * 8 + e] - mu) * rstd * wi[c] + bi[c]);
            }
            *(u16x8*)&A[pl][ht * 64 + h * 8] = o8;
        }
    }
    {
        const int c = tid >> 1, seg = tid & 1;
        #pragma unroll
        for (int e = 0; e < 8; ++e) {
            u16x8 vv = *(const u16x8*)(x_cm + (size_t)c * CPITCH + p0 + seg * 64 + e * 8);
            *(u16x8*)&Bt[c][seg * 64 + e * 8] = vv;
        }
    }
    __syncthreads();

    bf16x8 afz[2][4];
    #pragma unroll
    for (int t = 0; t < 2; ++t)
        #pragma unroll
        for (int ks = 0; ks < 4; ++ks)
            afz[t][ks] = *(const bf16x8*)&A[wave * 32 + t * 16 + m][ks * 32 + q * 8];
    __syncthreads();

    {
        float v[64];
        #pragma unroll
        for (int e = 0; e < 64; ++e) v[e] = b2f(Bt[ht * 64 + e][pl]);
        float s = 0.f, s2 = 0.f;
        #pragma unroll
        for (int e = 0; e < 64; ++e) { s += v[e]; s2 += v[e] * v[e]; }
        s  += __shfl_xor(s, 1);
        s2 += __shfl_xor(s2, 1);
        const float mu   = s * (1.0f / CC);
        const float rstd = rsqrtf(s2 * (1.0f / CC) - mu * mu + 1e-5f);
        #pragma unroll
        for (int h = 0; h < 8; ++h) {
            u16x8 o8;
            #pragma unroll
            for (int e = 0; e < 8; ++e) {
                const int c = ht * 64 + h * 8 + e;
                o8[e] = f2b((v[h * 8 + e] - mu) * rstd * wo[c] + bo[c]);
            }
            *(u16x8*)&A[pl][ht * 64 + h * 8] = o8;
        }
    }
    __syncthreads();

    bf16x8 afx[2][4];
    #pragma unroll
    for (int t = 0; t < 2; ++t)
        #pragma unroll
        for (int ks = 0; ks < 4; ++ks)
            afx[t][ks] = *(const bf16x8*)&A[wave * 32 + t * 16 + m][ks * 32 + q * 8];

    for (int cb = 0; cb < 8; ++cb) {
        const int o = cb * 16 + m;
        const float gb0 = gbv[o], zb0 = zbv[o];
        f32x4 accg[2], accx[2];
        #pragma unroll
        for (int t = 0; t < 2; ++t) {
            accg[t] = f32x4{ gb0, gb0, gb0, gb0 };
            accx[t] = f32x4{ zb0, zb0, zb0, zb0 };
        }
        const u16* wpg = wpk + ((size_t)((4 * 8 + cb) * 4)) * 512 + (size_t)lane * 8;
        const u16* wpz = wpk + ((size_t)((5 * 8 + cb) * 4)) * 512 + (size_t)lane * 8;
        bf16x8 wg[4], wz[4];
        #pragma unroll
        for (int ks = 0; ks < 4; ++ks) {
            wg[ks] = *(const bf16x8*)(wpg + ks * 512);
            wz[ks] = *(const bf16x8*)(wpz + ks * 512);
        }
        #pragma unroll
        for (int ks = 0; ks < 4; ++ks)
            #pragma unroll
            for (int t = 0; t < 2; ++t) {
                accg[t] = __builtin_amdgcn_mfma_f32_16x16x32_bf16(
                            afz[t][ks], wg[ks], accg[t], 0, 0, 0);
                accx[t] = __builtin_amdgcn_mfma_f32_16x16x32_bf16(
                            afx[t][ks], wz[ks], accx[t], 0, 0, 0);
            }
        #pragma unroll
        for (int t = 0; t < 2; ++t)
            #pragma unroll
            for (int r = 0; r < 4; ++r) {
                const size_t p = p0 + wave * 32 + t * 16 + q * 4 + r;
                out[p * CC + o] = accx[t][r] * sigm(accg[t][r]);
            }
    }
}

// ---------------------------------------------------------------------------
extern "C" void kernel_launch(void* const* d_in, const int* in_sizes, int n_in,
                              void* d_out, int out_size, void* d_ws, size_t ws_size,
                              hipStream_t stream)
{
    const float* z    = (const float*)d_in[0];
    const float* mask = (const float*)d_in[1];
    const float* wi   = (const float*)d_in[2];
    const float* bi   = (const float*)d_in[3];
    const float* apw  = (const float*)d_in[4];
    const float* apb  = (const float*)d_in[5];
    const float* agw  = (const float*)d_in[6];
    const float* agb  = (const float*)d_in[7];
    const float* bpw  = (const float*)d_in[8];
    const float* bpb  = (const float*)d_in[9];
    const float* bgw  = (const float*)d_in[10];
    const float* bgb  = (const float*)d_in[11];
    const float* gw   = (const float*)d_in[12];
    const float* gb   = (const float*)d_in[13];
    const float* zw   = (const float*)d_in[14];
    const float* zb   = (const float*)d_in[15];
    const float* wo   = (const float*)d_in[16];
    const float* bo   = (const float*)d_in[17];

    u16* a_cm = (u16*)d_ws;                          // [c][CPITCH] bf16
    u16* b_cm = a_cm + (size_t)CC * CPITCH;
    u16* x_cm = b_cm + (size_t)CC * CPITCH;
    u16* w_pk = x_cm + (size_t)CC * CPITCH;          // 192 KiB packed frags
    u16* zn_pm = w_pk + (size_t)6 * 16384;           // 64 MiB zn handoff
    float* s12 = (float*)(zn_pm + (size_t)NPOS * CC);// 1 KiB fold constants
    float* out = (float*)d_out;

    const size_t need_zn =
        ((size_t)CC * CPITCH * 3 + 6 * 16384 + (size_t)NPOS * CC) * sizeof(u16)
        + 256 * sizeof(float);
    const bool use_zn = (ws_size == 0) || (ws_size >= need_zn);
    if (!use_zn) zn_pm = nullptr;

    W6 w6; w6.p[0] = agw; w6.p[1] = apw; w6.p[2] = bgw; w6.p[3] = bpw;
    w6.p[4] = gw; w6.p[5] = zw;

    k0_pack<<<6 * 16384 / 256, 256, 0, stream>>>(w6, use_zn ? wo : nullptr, w_pk);
    if (use_zn)
        k0_s12<<<1, 128, 0, stream>>>(zw, wo, bo, s12);
    k1_ln_proj<<<NPOS / 64, 128, 0, stream>>>(z, mask, wi, bi, w_pk,
                                              agb, apb, bgb, bpb, a_cm, b_cm, zn_pm);
    k2_gemm<<<128 * 16, 256, 0, stream>>>(a_cm, b_cm, x_cm);
    if (use_zn)
        k3_out_fold<<<NPOS / 128, 256, 0, stream>>>(out, x_cm, zn_pm,
                                                    w_pk, s12, gb, zb);
    else
        k3_out<<<NPOS / 128, 256, 0, stream>>>(out, x_cm, z, wi, bi, wo, bo,
                                               w_pk, gb, zb);
}

// Round 7
// 473.259 us; speedup vs baseline: 1.0469x; 1.0469x over previous
//
#include <hip/hip_runtime.h>
#include <stddef.h>

#define NN 512
#define CC 128
#define NPOS (NN*NN)
#define CPITCH (NPOS + 512)

typedef unsigned short u16;
typedef unsigned int   u32;
typedef u16  u16x4  __attribute__((ext_vector_type(4)));
typedef u16  u16x8  __attribute__((ext_vector_type(8)));
typedef __bf16 bf16x8 __attribute__((ext_vector_type(8)));
typedef float f32x4  __attribute__((ext_vector_type(4)));

__device__ __forceinline__ float b2f(u16 u) {
    union { u32 i; float f; } w; w.i = ((u32)u) << 16; return w.f;
}
__device__ __forceinline__ u16 f2b(float f) {
    return __builtin_bit_cast(u16, (__bf16)f);
}
__device__ __forceinline__ float sigm(float x) { return 1.0f / (1.0f + __expf(-x)); }

__device__ __forceinline__ void gld16(const u16* g, u16* l) {
    __builtin_amdgcn_global_load_lds(
        (const __attribute__((address_space(1))) u32*)g,
        (__attribute__((address_space(3))) u32*)l, 16, 0, 0);
}

struct W6 { const float* p[6]; };   // 0:agw 1:apw 2:bgw 3:bpw 4:gw 5:zw

// ---------------------------------------------------------------------------
// K0: pack 6 [128x128] f32 weight matrices into bf16 MFMA-fragment order.
// ---------------------------------------------------------------------------
__global__ __launch_bounds__(256) void k0_pack(W6 w, u16* __restrict__ dst)
{
    const int i = blockIdx.x * 256 + threadIdx.x;     // 6*16384 total
    const int mt = i >> 14, r = i & 16383;
    const int cb = r >> 11, ks = (r >> 9) & 3, lane = (r >> 3) & 63, j = r & 7;
    const int row = cb * 16 + (lane & 15);
    const int col = ks * 32 + (lane >> 4) * 8 + j;
    dst[i] = f2b(w.p[mt][row * 128 + col]);
}

// ---------------------------------------------------------------------------
// K1: LayerNorm(z) + 4 gated projections, MFMA. r4 structure (best measured):
// 64 positions/block, 128 threads; writes zn (bf16 position-major) for k3.
// ---------------------------------------------------------------------------
__global__ __launch_bounds__(128) void k1_ln_proj(
    const float* __restrict__ z,  const float* __restrict__ mask,
    const float* __restrict__ wi, const float* __restrict__ bi,
    const u16* __restrict__ wpk,
    const float* __restrict__ agb, const float* __restrict__ apb,
    const float* __restrict__ bgb, const float* __restrict__ bpb,
    u16* __restrict__ a_cm, u16* __restrict__ b_cm,
    u16* __restrict__ zn_pm)
{
    __shared__ u16 zn[64][136];   // bf16 normalized z, pitch 136
    const int tid = threadIdx.x;
    const size_t p0 = (size_t)blockIdx.x * 64;

    {   // ---- LayerNorm, coalesced: 32-lane group co-owns one row ----
        const float* zt = z + p0 * CC;
        const int g  = tid >> 5;            // row-group
        const int c4 = (tid & 31) * 4;      // channel base
        const f32x4 wi4 = *(const f32x4*)(wi + c4);
        const f32x4 bi4 = *(const f32x4*)(bi + c4);
        f32x4 v[16];
        #pragma unroll
        for (int h = 0; h < 16; ++h)
            v[h] = *(const f32x4*)(zt + h * 512 + tid * 4);
        #pragma unroll
        for (int h = 0; h < 16; ++h) {
            float s  = (v[h][0] + v[h][1]) + (v[h][2] + v[h][3]);
            float s2 = (v[h][0]*v[h][0] + v[h][1]*v[h][1])
                     + (v[h][2]*v[h][2] + v[h][3]*v[h][3]);
            #pragma unroll
            for (int ms = 1; ms <= 16; ms <<= 1) {
                s  += __shfl_xor(s,  ms);
                s2 += __shfl_xor(s2, ms);
            }
            const float mu   = s * (1.0f / CC);
            const float rstd = rsqrtf(s2 * (1.0f / CC) - mu * mu + 1e-5f);
            u16x4 o4;
            #pragma unroll
            for (int e = 0; e < 4; ++e) {
                const float nw = rstd * wi4[e];
                o4[e] = f2b(v[h][e] * nw + __builtin_fmaf(-mu, nw, bi4[e]));
            }
            *(u16x4*)&zn[h * 4 + g][c4] = o4;
            if (zn_pm)
                *(u16x4*)(zn_pm + (p0 + h * 4 + g) * CC + c4) = o4;
        }
    }
    __syncthreads();

    const int wave = tid >> 6, lane = tid & 63;
    const int m = lane & 15, q = lane >> 4;

    bf16x8 af[2][4];
    #pragma unroll
    for (int t = 0; t < 2; ++t)
        #pragma unroll
        for (int ks = 0; ks < 4; ++ks)
            af[t][ks] = *(const bf16x8*)&zn[wave * 32 + t * 16 + m][ks * 32 + q * 8];

    f32x4 mkv[2];
    #pragma unroll
    for (int t = 0; t < 2; ++t)
        mkv[t] = *(const f32x4*)(mask + p0 + wave * 32 + t * 16 + q * 4);

    const float* Bv[4] = { agb, apb, bgb, bpb };

    for (int cb = 0; cb < 8; ++cb) {
        const int o = cb * 16 + m;
        f32x4 res[4][2];
        #pragma unroll
        for (int mt = 0; mt < 4; ++mt) {
            const float bvv = Bv[mt][o];
            #pragma unroll
            for (int t = 0; t < 2; ++t) res[mt][t] = f32x4{ bvv, bvv, bvv, bvv };
            const u16* wp = wpk + ((size_t)((mt * 8 + cb) * 4)) * 512 + (size_t)lane * 8;
            bf16x8 wf[4];
            #pragma unroll
            for (int ks = 0; ks < 4; ++ks) wf[ks] = *(const bf16x8*)(wp + ks * 512);
            #pragma unroll
            for (int ks = 0; ks < 4; ++ks)
                #pragma unroll
                for (int t = 0; t < 2; ++t)
                    res[mt][t] = __builtin_amdgcn_mfma_f32_16x16x32_bf16(
                                   af[t][ks], wf[ks], res[mt][t], 0, 0, 0);
        }
        #pragma unroll
        for (int t = 0; t < 2; ++t) {
            u16x4 av, bv;
            #pragma unroll
            for (int r = 0; r < 4; ++r) {
                const float mk = mkv[t][r];
                av[r] = f2b(mk * sigm(res[0][t][r]) * res[1][t][r]);
                bv[r] = f2b(mk * sigm(res[2][t][r]) * res[3][t][r]);
            }
            const size_t off = (size_t)o * CPITCH + p0 + wave * 32 + t * 16 + q * 4;
            *(u16x4*)(a_cm + off) = av;
            *(u16x4*)(b_cm + off) = bv;
        }
    }
}

// ---------------------------------------------------------------------------
// K2: per-channel 512x512x512 NT GEMM, XCD-affine.
// NEW: true K=32 ping-pong double-buffer in the same 32 KB LDS.
// Old loop: barrier -> issue loads -> barrier(vmcnt0 drain, compute idle) ->
// compute. New loop: issue NEXT tile's loads -> compute CURRENT tile (loads
// in flight under the MFMAs) -> one barrier. Same swizzle, same epilogue.
// ---------------------------------------------------------------------------
__global__ __launch_bounds__(256) void k2_gemm(
    const u16* __restrict__ A, const u16* __restrict__ B, u16* __restrict__ X)
{
    __shared__ u16 As[2][128][32];
    __shared__ u16 Bs[2][128][32];
    const int tid = threadIdx.x;
    const int bx  = blockIdx.x;
    const int xcd  = bx & 7;
    const int slot = bx >> 3;              // 0..255 per XCD
    const int c    = (slot >> 4) * 8 + xcd;
    const int tile = slot & 15;
    const int i0   = (tile >> 2) * 128;
    const int j0   = (tile & 3) * 128;
    const size_t cbase = (size_t)c * CPITCH;
    const u16* Ac = A + cbase;
    const u16* Bc = B + cbase;

    const int wave = tid >> 6, lane = tid & 63;
    const int wm = wave >> 1, wn = wave & 1;
    const int m = lane & 15, q = lane >> 4;

    f32x4 acc[4][4];
    const f32x4 zero = { 0.f, 0.f, 0.f, 0.f };
    #pragma unroll
    for (int mt = 0; mt < 4; ++mt)
        #pragma unroll
        for (int nt = 0; nt < 4; ++nt) acc[mt][nt] = zero;

    // staging geometry: id = ps*256+tid in [0,512): row = id>>2,
    // LDS slot s = id&3 holds global col-group g = s ^ ((row>>1)&3).
    // prologue: stage tile 0 into buffer 0
    #pragma unroll
    for (int ps = 0; ps < 2; ++ps) {
        const int id = ps * 256 + tid;
        const int rw = id >> 2;
        const int g  = (id & 3) ^ ((rw >> 1) & 3);
        gld16(Ac + (size_t)(i0 + rw) * NN + g * 8, &As[0][0][0] + id * 8);
        gld16(Bc + (size_t)(j0 + rw) * NN + g * 8, &Bs[0][0][0] + id * 8);
    }
    __syncthreads();

    int cur = 0;
    for (int kt = 0; kt < 16; ++kt) {
        if (kt < 15) {   // issue next tile's loads into the other buffer
            const int nb = cur ^ 1;
            #pragma unroll
            for (int ps = 0; ps < 2; ++ps) {
                const int id = ps * 256 + tid;
                const int rw = id >> 2;
                const int g  = (id & 3) ^ ((rw >> 1) & 3);
                const size_t goff = (size_t)((kt + 1) * 32 + g * 8);
                gld16(Ac + (size_t)(i0 + rw) * NN + goff, &As[nb][0][0] + id * 8);
                gld16(Bc + (size_t)(j0 + rw) * NN + goff, &Bs[nb][0][0] + id * 8);
            }
        }
        // compute current buffer while next tile's loads are in flight
        bf16x8 af[4], bf[4];
        #pragma unroll
        for (int mt = 0; mt < 4; ++mt) {
            const int row = wm * 64 + mt * 16 + m;
            const int slt = q ^ ((row >> 1) & 3);
            af[mt] = *(const bf16x8*)&As[cur][row][slt * 8];
        }
        #pragma unroll
        for (int nt = 0; nt < 4; ++nt) {
            const int row = wn * 64 + nt * 16 + m;
            const int slt = q ^ ((row >> 1) & 3);
            bf[nt] = *(const bf16x8*)&Bs[cur][row][slt * 8];
        }
        #pragma unroll
        for (int mt = 0; mt < 4; ++mt)
            #pragma unroll
            for (int nt = 0; nt < 4; ++nt)
                acc[mt][nt] = __builtin_amdgcn_mfma_f32_16x16x32_bf16(
                                af[mt], bf[nt], acc[mt][nt], 0, 0, 0);
        __syncthreads();   // drains vmcnt after compute covered the latency
        cur ^= 1;
    }

    #pragma unroll
    for (int mt = 0; mt < 4; ++mt) {
        #pragma unroll
        for (int r = 0; r < 4; ++r) {
            const int i = i0 + wm * 64 + mt * 16 + q * 4 + r;
            #pragma unroll
            for (int nt = 0; nt < 4; ++nt) {
                const int j = j0 + wn * 64 + nt * 16 + m;
                X[cbase + (size_t)i * NN + j] = f2b(acc[mt][nt][r]);
            }
        }
    }
}

// ---------------------------------------------------------------------------
// K3: out = (LN(x)@z_w^T + z_b) * sigmoid(zn@g_w^T + g_b), zn from handoff.
// r4 version (best measured).
// ---------------------------------------------------------------------------
__global__ __launch_bounds__(256) void k3_out_zn(
    float* __restrict__ out, const u16* __restrict__ x_cm,
    const u16* __restrict__ zn_pm,
    const float* __restrict__ wo, const float* __restrict__ bo,
    const u16* __restrict__ wpk,
    const float* __restrict__ gbv, const float* __restrict__ zbv)
{
    __shared__ u16 A[128][136];    // xn
    __shared__ u16 Bt[128][136];   // x tile, channel-major [c][p]
    const int tid = threadIdx.x;
    const size_t p0 = (size_t)blockIdx.x * 128;
    const int wave = tid >> 6, lane = tid & 63;
    const int m = lane & 15, q = lane >> 4;
    const int pl = tid >> 1, ht = tid & 1;

    {
        const int c = tid >> 1, seg = tid & 1;
        #pragma unroll
        for (int e = 0; e < 8; ++e) {
            u16x8 vv = *(const u16x8*)(x_cm + (size_t)c * CPITCH + p0 + seg * 64 + e * 8);
            *(u16x8*)&Bt[c][seg * 64 + e * 8] = vv;
        }
    }
    bf16x8 afz[2][4];
    #pragma unroll
    for (int t = 0; t < 2; ++t)
        #pragma unroll
        for (int ks = 0; ks < 4; ++ks)
            afz[t][ks] = *(const bf16x8*)(zn_pm
                           + (p0 + wave * 32 + t * 16 + m) * CC + ks * 32 + q * 8);
    __syncthreads();

    {
        float v[64];
        #pragma unroll
        for (int e = 0; e < 64; ++e) v[e] = b2f(Bt[ht * 64 + e][pl]);
        float s = 0.f, s2 = 0.f;
        #pragma unroll
        for (int e = 0; e < 64; ++e) { s += v[e]; s2 += v[e] * v[e]; }
        s  += __shfl_xor(s, 1);
        s2 += __shfl_xor(s2, 1);
        const float mu   = s * (1.0f / CC);
        const float rstd = rsqrtf(s2 * (1.0f / CC) - mu * mu + 1e-5f);
        #pragma unroll
        for (int h = 0; h < 8; ++h) {
            u16x8 o8;
            #pragma unroll
            for (int e = 0; e < 8; ++e) {
                const int c = ht * 64 + h * 8 + e;
                o8[e] = f2b((v[h * 8 + e] - mu) * rstd * wo[c] + bo[c]);
            }
            *(u16x8*)&A[pl][ht * 64 + h * 8] = o8;
        }
    }
    __syncthreads();

    bf16x8 afx[2][4];
    #pragma unroll
    for (int t = 0; t < 2; ++t)
        #pragma unroll
        for (int ks = 0; ks < 4; ++ks)
            afx[t][ks] = *(const bf16x8*)&A[wave * 32 + t * 16 + m][ks * 32 + q * 8];

    for (int cb = 0; cb < 8; ++cb) {
        const int o = cb * 16 + m;
        const float gb0 = gbv[o], zb0 = zbv[o];
        f32x4 accg[2], accx[2];
        #pragma unroll
        for (int t = 0; t < 2; ++t) {
            accg[t] = f32x4{ gb0, gb0, gb0, gb0 };
            accx[t] = f32x4{ zb0, zb0, zb0, zb0 };
        }
        const u16* wpg = wpk + ((size_t)((4 * 8 + cb) * 4)) * 512 + (size_t)lane * 8;
        const u16* wpz = wpk + ((size_t)((5 * 8 + cb) * 4)) * 512 + (size_t)lane * 8;
        bf16x8 wg[4], wz[4];
        #pragma unroll
        for (int ks = 0; ks < 4; ++ks) {
            wg[ks] = *(const bf16x8*)(wpg + ks * 512);
            wz[ks] = *(const bf16x8*)(wpz + ks * 512);
        }
        #pragma unroll
        for (int ks = 0; ks < 4; ++ks)
            #pragma unroll
            for (int t = 0; t < 2; ++t) {
                accg[t] = __builtin_amdgcn_mfma_f32_16x16x32_bf16(
                            afz[t][ks], wg[ks], accg[t], 0, 0, 0);
                accx[t] = __builtin_amdgcn_mfma_f32_16x16x32_bf16(
                            afx[t][ks], wz[ks], accx[t], 0, 0, 0);
            }
        #pragma unroll
        for (int t = 0; t < 2; ++t)
            #pragma unroll
            for (int r = 0; r < 4; ++r) {
                const size_t p = p0 + wave * 32 + t * 16 + q * 4 + r;
                out[p * CC + o] = accx[t][r] * sigm(accg[t][r]);
            }
    }
}

// ---------------------------------------------------------------------------
// K3 (legacy fallback, used only if workspace too small for zn handoff).
// ---------------------------------------------------------------------------
__global__ __launch_bounds__(256) void k3_out(
    float* __restrict__ out, const u16* __restrict__ x_cm,
    const float* __restrict__ z,
    const float* __restrict__ wi, const float* __restrict__ bi,
    const float* __restrict__ wo, const float* __restrict__ bo,
    const u16* __restrict__ wpk,
    const float* __restrict__ gbv, const float* __restrict__ zbv)
{
    __shared__ u16 A[128][136];
    __shared__ u16 Bt[128][136];
    const int tid = threadIdx.x;
    const size_t p0 = (size_t)blockIdx.x * 128;
    const int wave = tid >> 6, lane = tid & 63;
    const int m = lane & 15, q = lane >> 4;
    const int pl = tid >> 1, ht = tid & 1;

    {
        const float* zr = z + (p0 + pl) * CC + ht * 64;
        float v[64];
        #pragma unroll
        for (int h = 0; h < 16; ++h) {
            f32x4 t = *(const f32x4*)(zr + h * 4);
            #pragma unroll
            for (int e = 0; e < 4; ++e) v[h * 4 + e] = t[e];
        }
        float s = 0.f, s2 = 0.f;
        #pragma unroll
        for (int e = 0; e < 64; ++e) { s += v[e]; s2 += v[e] * v[e]; }
        s  += __shfl_xor(s, 1);
        s2 += __shfl_xor(s2, 1);
        const float mu   = s * (1.0f / CC);
        const float rstd = rsqrtf(s2 * (1.0f / CC) - mu * mu + 1e-5f);
        #pragma unroll
        for (int h = 0; h < 8; ++h) {
            u16x8 o8;
            #pragma unroll
            for (int e = 0; e < 8; ++e) {
                const int c = ht * 64 + h * 8 + e;
                o8[e] = f2b((v[h * 8 + e] - mu) * rstd * wi[c] + bi[c]);
            }
            *(u16x8*)&A[pl][ht * 64 + h * 8] = o8;
        }
    }
    {
        const int c = tid >> 1, seg = tid & 1;
        #pragma unroll
        for (int e = 0; e < 8; ++e) {
            u16x8 vv = *(const u16x8*)(x_cm + (size_t)c * CPITCH + p0 + seg * 64 + e * 8);
            *(u16x8*)&Bt[c][seg * 64 + e * 8] = vv;
        }
    }
    __syncthreads();

    bf16x8 afz[2][4];
    #pragma unroll
    for (int t = 0; t < 2; ++t)
        #pragma unroll
        for (int ks = 0; ks < 4; ++ks)
            afz[t][ks] = *(const bf16x8*)&A[wave * 32 + t * 16 + m][ks * 32 + q * 8];
    __syncthreads();

    {
        float v[64];
        #pragma unroll
        for (int e = 0; e < 64; ++e) v[e] = b2f(Bt[ht * 64 + e][pl]);
        float s = 0.f, s2 = 0.f;
        #pragma unroll
        for (int e = 0; e < 64; ++e) { s += v[e]; s2 += v[e] * v[e]; }
        s  += __shfl_xor(s, 1);
        s2 += __shfl_xor(s2, 1);
        const float mu   = s * (1.0f / CC);
        const float rstd = rsqrtf(s2 * (1.0f / CC) - mu * mu + 1e-5f);
        #pragma unroll
        for (int h = 0; h < 8; ++h) {
            u16x8 o8;
            #pragma unroll
            for (int e = 0; e < 8; ++e) {
                const int c = ht * 64 + h * 8 + e;
                o8[e] = f2b((v[h * 8 + e] - mu) * rstd * wo[c] + bo[c]);
            }
            *(u16x8*)&A[pl][ht * 64 + h * 8] = o8;
        }
    }
    __syncthreads();

    bf16x8 afx[2][4];
    #pragma unroll
    for (int t = 0; t < 2; ++t)
        #pragma unroll
        for (int ks = 0; ks < 4; ++ks)
            afx[t][ks] = *(const bf16x8*)&A[wave * 32 + t * 16 + m][ks * 32 + q * 8];

    for (int cb = 0; cb < 8; ++cb) {
        const int o = cb * 16 + m;
        const float gb0 = gbv[o], zb0 = zbv[o];
        f32x4 accg[2], accx[2];
        #pragma unroll
        for (int t = 0; t < 2; ++t) {
            accg[t] = f32x4{ gb0, gb0, gb0, gb0 };
            accx[t] = f32x4{ zb0, zb0, zb0, zb0 };
        }
        const u16* wpg = wpk + ((size_t)((4 * 8 + cb) * 4)) * 512 + (size_t)lane * 8;
        const u16* wpz = wpk + ((size_t)((5 * 8 + cb) * 4)) * 512 + (size_t)lane * 8;
        bf16x8 wg[4], wz[4];
        #pragma unroll
        for (int ks = 0; ks < 4; ++ks) {
            wg[ks] = *(const bf16x8*)(wpg + ks * 512);
            wz[ks] = *(const bf16x8*)(wpz + ks * 512);
        }
        #pragma unroll
        for (int ks = 0; ks < 4; ++ks)
            #pragma unroll
            for (int t = 0; t < 2; ++t) {
                accg[t] = __builtin_amdgcn_mfma_f32_16x16x32_bf16(
                            afz[t][ks], wg[ks], accg[t], 0, 0, 0);
                accx[t] = __builtin_amdgcn_mfma_f32_16x16x32_bf16(
                            afx[t][ks], wz[ks], accx[t], 0, 0, 0);
            }
        #pragma unroll
        for (int t = 0; t < 2; ++t)
            #pragma unroll
            for (int r = 0; r < 4; ++r) {
                const size_t p = p0 + wave * 32 + t * 16 + q * 4 + r;
                out[p * CC + o] = accx[t][r] * sigm(accg[t][r]);
            }
    }
}

// ---------------------------------------------------------------------------
extern "C" void kernel_launch(void* const* d_in, const int* in_sizes, int n_in,
                              void* d_out, int out_size, void* d_ws, size_t ws_size,
                              hipStream_t stream)
{
    const float* z    = (const float*)d_in[0];
    const float* mask = (const float*)d_in[1];
    const float* wi   = (const float*)d_in[2];
    const float* bi   = (const float*)d_in[3];
    const float* apw  = (const float*)d_in[4];
    const float* apb  = (const float*)d_in[5];
    const float* agw  = (const float*)d_in[6];
    const float* agb  = (const float*)d_in[7];
    const float* bpw  = (const float*)d_in[8];
    const float* bpb  = (const float*)d_in[9];
    const float* bgw  = (const float*)d_in[10];
    const float* bgb  = (const float*)d_in[11];
    const float* gw   = (const float*)d_in[12];
    const float* gb   = (const float*)d_in[13];
    const float* zw   = (const float*)d_in[14];
    const float* zb   = (const float*)d_in[15];
    const float* wo   = (const float*)d_in[16];
    const float* bo   = (const float*)d_in[17];

    u16* a_cm = (u16*)d_ws;                          // [c][CPITCH] bf16
    u16* b_cm = a_cm + (size_t)CC * CPITCH;
    u16* x_cm = b_cm + (size_t)CC * CPITCH;
    u16* w_pk = x_cm + (size_t)CC * CPITCH;          // 192 KiB packed frags
    u16* zn_pm = w_pk + (size_t)6 * 16384;           // 64 MiB zn handoff
    float* out = (float*)d_out;

    const size_t need_zn =
        ((size_t)CC * CPITCH * 3 + 6 * 16384 + (size_t)NPOS * CC) * sizeof(u16);
    const bool use_zn = (ws_size == 0) || (ws_size >= need_zn);
    if (!use_zn) zn_pm = nullptr;

    W6 w6; w6.p[0] = agw; w6.p[1] = apw; w6.p[2] = bgw; w6.p[3] = bpw;
    w6.p[4] = gw; w6.p[5] = zw;

    k0_pack<<<6 * 16384 / 256, 256, 0, stream>>>(w6, w_pk);
    k1_ln_proj<<<NPOS / 64, 128, 0, stream>>>(z, mask, wi, bi, w_pk,
                                              agb, apb, bgb, bpb, a_cm, b_cm, zn_pm);
    k2_gemm<<<128 * 16, 256, 0, stream>>>(a_cm, b_cm, x_cm);
    if (use_zn)
        k3_out_zn<<<NPOS / 128, 256, 0, stream>>>(out, x_cm, zn_pm, wo, bo,
                                                  w_pk, gb, zb);
    else
        k3_out<<<NPOS / 128, 256, 0, stream>>>(out, x_cm, z, wi, bi, wo, bo,
                                               w_pk, gb, zb);
}